// Round 1
// baseline (155.914 us; speedup 1.0000x reference)
//
#include <hip/hip_runtime.h>

// Problem constants (DeepDFTinv message block): B=2, P=4096, A=96, G=1, F=32, E=20
#define NB   2
#define NP   4096
#define NA   96
#define NF   32
#define NE   20
#define NBP  (NB*NP)

typedef __attribute__((ext_vector_type(8)))  short bf16x8;   // 8 bf16 = 4 VGPRs (MFMA A/B frag)
typedef __attribute__((ext_vector_type(16))) float f32x16;   // 32x32 MFMA C/D frag

union Frag { bf16x8 v; int i[4]; };

// RNE float -> bf16 bits
__device__ __forceinline__ unsigned short f2bf(float x) {
  union { float f; unsigned u; } c; c.f = x;
  unsigned r = c.u + 0x7fffu + ((c.u >> 16) & 1u);
  return (unsigned short)(r >> 16);
}
__device__ __forceinline__ int pk2(float lo, float hi) {
  return (int)((unsigned)f2bf(lo) | ((unsigned)f2bf(hi) << 16));
}
// shifted softplus: log1p(exp(x)) - log(2), stable form
__device__ __forceinline__ float ssp_f(float x) {
  float e = __expf(-fabsf(x));
  return fmaxf(x, 0.0f) + __logf(1.0f + e) - 0.69314718056f;
}
__device__ __forceinline__ f32x16 mfma32(const Frag a, const Frag b, f32x16 c) {
  return __builtin_amdgcn_mfma_f32_32x32x16_bf16(a.v, b.v, c, 0, 0, 0);
}
// Build C-init vector from 32-float LDS bias array, rows = (r&3)+8*(r>>2)+4*hw
__device__ __forceinline__ f32x16 ld_bias16(const float* base /* = smb_sec + 4*hw */) {
  const float4* p = reinterpret_cast<const float4*>(base);
  float4 q0 = p[0], q1 = p[2], q2 = p[4], q3 = p[6];
  f32x16 c;
  c[0]=q0.x;  c[1]=q0.y;  c[2]=q0.z;  c[3]=q0.w;
  c[4]=q1.x;  c[5]=q1.y;  c[6]=q1.z;  c[7]=q1.w;
  c[8]=q2.x;  c[9]=q2.y;  c[10]=q2.z; c[11]=q2.w;
  c[12]=q3.x; c[13]=q3.y; c[14]=q3.z; c[15]=q3.w;
  return c;
}

// ---------- prep: tgt = sr @ Wt  -> d_out (read back by its own block only)
//            src = scalar @ Ws + b1n -> d_ws ----------
__global__ __launch_bounds__(256)
void prep_kernel(const float* __restrict__ scalar,
                 const float* __restrict__ sr,
                 const float* __restrict__ W1n,
                 const float* __restrict__ b1n,
                 float* __restrict__ tgt_out,
                 float* __restrict__ src_ws)
{
  int i = blockIdx.x * 256 + threadIdx.x;
  int f = i & 31;
  int row = i >> 5;
  if (row < NBP) {                       // tgt rows
    const float* x = sr + row * NF;
    float a = 0.0f;
#pragma unroll
    for (int k = 0; k < NF; ++k) a = fmaf(x[k], W1n[(NF + k) * NF + f], a);
    tgt_out[i] = a;
  } else {                               // src rows (192 of them), fold b1n
    int ba = row - NBP;
    const float* x = scalar + ba * NF;
    float a = b1n[f];
#pragma unroll
    for (int k = 0; k < NF; ++k) a = fmaf(x[k], W1n[k * NF + f], a);
    src_ws[ba * NF + f] = a;
  }
}

// ---------- main: one wave handles one (b,p); 2 (b,p) per block ----------
// All GEMMs computed transposed: D = W^T (MxK) * X^T (KxN=a), so that GEMM1's
// C-layout (col=lane&31=a) feeds GEMM2's B-layout (n=lane&31=a) after
// cvt_pk_bf16 + v_permlane32_swap (T12 pattern).
__global__ __launch_bounds__(64, 3)
void fused_main(const float* __restrict__ expansion,
                const float* __restrict__ mask,
                const float* __restrict__ edge_dist,
                const float* __restrict__ W1e,
                const float* __restrict__ b1e,
                const float* __restrict__ W2e,
                const float* __restrict__ b2e,
                const float* __restrict__ W2n,
                const float* __restrict__ b2n,
                const float* __restrict__ src_ws,
                float* out)
{
  const int lane = threadIdx.x;
  const int col  = lane & 31;    // matrix column = a within 32-tile
  const int hw   = lane >> 5;    // half-wave

  __shared__ __align__(16) float smb[128];   // [0:32)=b1e [32:64)=b2e [64:96)=b2n [96:128)=out staging
  if (lane < 32) {
    smb[lane]      = b1e[lane];
    smb[32 + lane] = b2e[lane];
    smb[64 + lane] = b2n[lane];
  }
  __syncthreads();

  // Preload transposed weight A-fragments. A-layout: row m = lane&31, k = 8*hw + elem.
  Frag a1s0, a1s1, a2s0, a2s1, a3s0, a3s1;
#pragma unroll
  for (int r = 0; r < 4; ++r) {
    const int k0 = 8 * hw + 2 * r;     // k-step 0: k = 0..15
    const int k1 = 16 + k0;            // k-step 1: k = 16..31
    // A1 = W1e^T (rows j=col, k=e; zero-pad e>=20)
    a1s0.i[r] = pk2(W1e[k0 * NF + col], W1e[(k0 + 1) * NF + col]);
    {
      int klo = (k1     < NE) ? k1     : (NE - 1);
      int khi = (k1 + 1 < NE) ? k1 + 1 : (NE - 1);
      float lo = W1e[klo * NF + col];
      float hi = W1e[khi * NF + col];
      lo = (k1     < NE) ? lo : 0.0f;
      hi = (k1 + 1 < NE) ? hi : 0.0f;
      a1s1.i[r] = pk2(lo, hi);
    }
    // A2 = W2e^T (rows f=col, k=j)
    a2s0.i[r] = pk2(W2e[k0 * NF + col], W2e[(k0 + 1) * NF + col]);
    a2s1.i[r] = pk2(W2e[k1 * NF + col], W2e[(k1 + 1) * NF + col]);
    // A3 = W2n^T (rows fo=col, k=fh)
    a3s0.i[r] = pk2(W2n[k0 * NF + col], W2n[(k0 + 1) * NF + col]);
    a3s1.i[r] = pk2(W2n[k1 * NF + col], W2n[(k1 + 1) * NF + col]);
  }

  const float* biasA = smb      + 4 * hw;   // b1e rows for this half
  const float* biasB = smb + 32 + 4 * hw;   // b2e
  const float* biasC = smb + 64 + 4 * hw;   // b2n

#pragma unroll 1
  for (int pi = 0; pi < 2; ++pi) {
    const int bp = blockIdx.x * 2 + pi;
    const int b  = bp >> 12;               // NP = 4096

    // tgt for this (b,p) lives in out[] (written by prep_kernel)
    const float* tg = out + bp * NF;
    float4 t0 = *reinterpret_cast<const float4*>(tg + 8 * hw);
    float4 t1 = *reinterpret_cast<const float4*>(tg + 8 * hw + 4);
    float4 t2 = *reinterpret_cast<const float4*>(tg + 16 + 8 * hw);
    float4 t3 = *reinterpret_cast<const float4*>(tg + 16 + 8 * hw + 4);

    const float* expb  = expansion + (size_t)bp * (NA * NE);
    const float* maskb = mask      + bp * NA;
    const float* distb = edge_dist + bp * NA;
    const float* srcb  = src_ws    + b * (NA * NF);

    f32x16 acc;
#pragma unroll
    for (int r = 0; r < 16; ++r) acc[r] = 0.0f;

#pragma unroll 1
    for (int t = 0; t < 3; ++t) {
      const int a = t * 32 + col;

      // ---- B1 = expansion^T fragment (k=e, n=a); per-lane 16/4-wide loads ----
      const float* ea = expb + a * NE;
      float4 e0 = *reinterpret_cast<const float4*>(ea + 8 * hw);
      float4 e1 = *reinterpret_cast<const float4*>(ea + 8 * hw + 4);
      float4 e2 = *reinterpret_cast<const float4*>(ea + 16);   // e=16..19 (half0 only)
      Frag b1f0, b1f1;
      b1f0.i[0] = pk2(e0.x, e0.y);
      b1f0.i[1] = pk2(e0.z, e0.w);
      b1f0.i[2] = pk2(e1.x, e1.y);
      b1f0.i[3] = pk2(e1.z, e1.w);
      b1f1.i[0] = hw ? 0 : pk2(e2.x, e2.y);
      b1f1.i[1] = hw ? 0 : pk2(e2.z, e2.w);
      b1f1.i[2] = 0;
      b1f1.i[3] = 0;

      // ---- GEMM1: H1^T[j][a] = b1e[j] + sum_e W1e[e][j]*exp[a][e] ----
      f32x16 d1 = ld_bias16(biasA);
      d1 = mfma32(a1s0, b1f0, d1);
      d1 = mfma32(a1s1, b1f1, d1);
#pragma unroll
      for (int r = 0; r < 16; ++r) d1[r] = ssp_f(d1[r]);

      // ---- C-layout f32 -> B-layout bf16 (cvt_pk + permlane32_swap) ----
      int u0 = pk2(d1[0],  d1[1]);
      int u1 = pk2(d1[2],  d1[3]);
      int u2 = pk2(d1[4],  d1[5]);
      int u3 = pk2(d1[6],  d1[7]);
      int u4 = pk2(d1[8],  d1[9]);
      int u5 = pk2(d1[10], d1[11]);
      int u6 = pk2(d1[12], d1[13]);
      int u7 = pk2(d1[14], d1[15]);
      asm("v_permlane32_swap_b32 %0, %1" : "+v"(u0), "+v"(u2));
      asm("v_permlane32_swap_b32 %0, %1" : "+v"(u1), "+v"(u3));
      asm("v_permlane32_swap_b32 %0, %1" : "+v"(u4), "+v"(u6));
      asm("v_permlane32_swap_b32 %0, %1" : "+v"(u5), "+v"(u7));
      Frag b2f0, b2f1;
      b2f0.i[0] = u0; b2f0.i[1] = u1; b2f0.i[2] = u2; b2f0.i[3] = u3;
      b2f1.i[0] = u4; b2f1.i[1] = u5; b2f1.i[2] = u6; b2f1.i[3] = u7;

      // ---- GEMM2: gates^T[f][a] = b2e[f] + sum_j W2e[j][f]*sspE^T[j][a] ----
      f32x16 d2 = ld_bias16(biasB);
      d2 = mfma32(a2s0, b2f0, d2);
      d2 = mfma32(a2s1, b2f1, d2);

      // mask * cutoff envelope; env = 1 - sigmoid(5*(d-3.5)) = 1/(1+e^{5(d-3.5)})
      const float mk = maskb[a];
      const float dd = distb[a];
      const float em = mk / (1.0f + __expf(5.0f * (dd - 3.5f)));

      // ---- nodes B-fragment built directly: ssp(src[a][fh] + tgt[fh]) ----
      const float* sa = srcb + a * NF;
      float4 s0 = *reinterpret_cast<const float4*>(sa + 8 * hw);
      float4 s1 = *reinterpret_cast<const float4*>(sa + 8 * hw + 4);
      float4 s2 = *reinterpret_cast<const float4*>(sa + 16 + 8 * hw);
      float4 s3 = *reinterpret_cast<const float4*>(sa + 16 + 8 * hw + 4);
      Frag b3f0, b3f1;
      b3f0.i[0] = pk2(ssp_f(s0.x + t0.x), ssp_f(s0.y + t0.y));
      b3f0.i[1] = pk2(ssp_f(s0.z + t0.z), ssp_f(s0.w + t0.w));
      b3f0.i[2] = pk2(ssp_f(s1.x + t1.x), ssp_f(s1.y + t1.y));
      b3f0.i[3] = pk2(ssp_f(s1.z + t1.z), ssp_f(s1.w + t1.w));
      b3f1.i[0] = pk2(ssp_f(s2.x + t2.x), ssp_f(s2.y + t2.y));
      b3f1.i[1] = pk2(ssp_f(s2.z + t2.z), ssp_f(s2.w + t2.w));
      b3f1.i[2] = pk2(ssp_f(s3.x + t3.x), ssp_f(s3.y + t3.y));
      b3f1.i[3] = pk2(ssp_f(s3.z + t3.z), ssp_f(s3.w + t3.w));

      // ---- GEMM3: nodes^T[fo][a] = b2n[fo] + sum_fh W2n[fh][fo]*sspN^T[fh][a] ----
      f32x16 d3 = ld_bias16(biasC);
      d3 = mfma32(a3s0, b3f0, d3);
      d3 = mfma32(a3s1, b3f1, d3);

      // ---- accumulate: out += mask*env * gates ⊙ nodes, summed over a ----
#pragma unroll
      for (int r = 0; r < 16; ++r) acc[r] = fmaf(em * d2[r], d3[r], acc[r]);
    }

    // reduce over columns a (32 lanes within each half-wave)
#pragma unroll
    for (int m = 1; m <= 16; m <<= 1) {
#pragma unroll
      for (int r = 0; r < 16; ++r) acc[r] += __shfl_xor(acc[r], m, 64);
    }

    __syncthreads();   // smb[96..] reuse across pi
    if (col == 0) {
#pragma unroll
      for (int r = 0; r < 16; ++r)
        smb[96 + ((r & 3) + 8 * (r >> 2) + 4 * hw)] = acc[r];
    }
    __syncthreads();
    if (lane < 32) out[bp * NF + lane] = smb[96 + lane];
  }
}

extern "C" void kernel_launch(void* const* d_in, const int* in_sizes, int n_in,
                              void* d_out, int out_size, void* d_ws, size_t ws_size,
                              hipStream_t stream) {
  const float* scalar    = (const float*)d_in[0];
  const float* sreciever = (const float*)d_in[1];
  const float* expansion = (const float*)d_in[2];
  const float* maskp     = (const float*)d_in[3];
  const float* edist     = (const float*)d_in[4];
  const float* W1e       = (const float*)d_in[5];
  const float* b1e       = (const float*)d_in[6];
  const float* W2e       = (const float*)d_in[7];
  const float* b2e       = (const float*)d_in[8];
  const float* W1n       = (const float*)d_in[9];
  const float* b1n       = (const float*)d_in[10];
  const float* W2n       = (const float*)d_in[11];
  const float* b2n       = (const float*)d_in[12];
  float* out    = (float*)d_out;
  float* src_ws = (float*)d_ws;     // 192*32 floats = 24 KB

  // (NBP + NB*NA) rows * 32 threads = 268288 = 1048 * 256 exactly
  prep_kernel<<<1048, 256, 0, stream>>>(scalar, sreciever, W1n, b1n, out, src_ws);
  fused_main<<<NBP / 2, 64, 0, stream>>>(expansion, maskp, edist,
                                         W1e, b1e, W2e, b2e, W2n, b2n,
                                         src_ws, out);
}